// Round 14
// baseline (32.500 us; speedup 1.0000x reference)
//
#include <hip/hip_runtime.h>
#include <stdint.h>

// Problem constants
#define NBATCH 1024
#define NQ 300
#define NC 80
#define QC 24000       // NQ * NC floats per batch
#define NF4 6000       // QC / 4
#define TOPK 300
#define RSEL 384u      // fast-path lower guard / slow-path select rank
#define NT 512         // threads per block (8 waves)
#define NWAVE 8
#define DEPTH 3        // per-wave LDS staging ring depth (3 KB/wave in flight)
#define NB1 2048       // slow-path coarse histogram buckets (key bits [31:21])
#define SH1 21
#define SH2 13         // slow-path refine bucket = (key >> 13) & 0xFF
#define SELCAP 1024    // candidate buffer
#define FINCAP 768     // finalist cap / fast-path upper guard
#define TAIL 368       // threads with a valid 12th round (6000 - 11*512)
#define THRESH 2.0f    // prefilter: candidate iff logit >= 2.0 (E[cnt]~546, sigma~23)
#define NBH 2048       // rank histogram buckets over score bits [20:10]
#define SBASE 0x3F600000u   // 0.875f; fast-path scores >= sigmoid(2.0)=0.8808

// order-preserving f32-bits -> u32 key (branchless)
__device__ __forceinline__ uint32_t xform(uint32_t u) {
    return u ^ (uint32_t)(((int32_t)u >> 31) | 0x80000000);
}

// monotone bucket map for score bits (exactness preserved via segment compare)
__device__ __forceinline__ uint32_t sbucket(uint32_t sbits) {
    int32_t d = (int32_t)(sbits - SBASE);
    d = d < 0 ? 0 : d;
    uint32_t bkt = ((uint32_t)d) >> 10;
    return bkt > (NBH - 1) ? (NBH - 1) : bkt;
}

// async global->LDS DMA, 16B per lane. ldst must be wave-uniform; HW writes
// lane L's 16B at ldst + L*16. gsrc is per-lane.
__device__ __forceinline__ void async_load16(const float4* gsrc, float4* ldst) {
    __builtin_amdgcn_global_load_lds(
        (const __attribute__((address_space(1))) void*)gsrc,
        (__attribute__((address_space(3))) void*)ldst,
        16, 0, 0);
}

// ---------------------------------------------------------------------------
// pick<NB,ZERO> (slow path only): hist[NB] finalized -> bucket from the top
// containing the rem-th largest + residual inside it. ZERO re-zeroes hist.
// NT=512 parameterization (wave0 lane sums 8 part entries).
// ---------------------------------------------------------------------------
template<int NB, bool ZERO>
__device__ __forceinline__ void pick(uint32_t* __restrict__ hist,
                                     uint32_t* __restrict__ part,
                                     uint32_t* __restrict__ gsufx,
                                     uint32_t* __restrict__ misc,
                                     int tid, uint32_t rem,
                                     uint32_t* bucket_out, uint32_t* rem_out) {
    constexpr int G = (NB >= NT) ? (NB / NT) : 1;
    const int base = tid * G;
    uint32_t h[G];
    uint32_t s = 0;
    if (base < NB) {
#pragma unroll
        for (int u = 0; u < G; ++u) { h[u] = hist[base + u]; s += h[u]; }
        if (ZERO) {
#pragma unroll
            for (int u = 0; u < G; ++u) hist[base + u] = 0;
        }
    } else {
#pragma unroll
        for (int u = 0; u < G; ++u) h[u] = 0;
    }
    part[tid] = s;
    __syncthreads();

    if (tid < 64) {
        uint32_t gs = 0;
#pragma unroll
        for (int u = 0; u < 8; ++u) gs += part[(tid << 3) + u];
        uint32_t S = gs;
#pragma unroll
        for (int off = 1; off < 64; off <<= 1) {
            uint32_t v = __shfl_down(S, off, 64);
            if (tid + off < 64) S += v;
        }
        gsufx[tid] = S;
        if (tid == 0) gsufx[64] = 0;
    }
    __syncthreads();

    const int g8 = tid >> 3;
    uint32_t A = gsufx[g8 + 1];
    for (int t2 = tid + 1; t2 < ((g8 + 1) << 3); ++t2) A += part[t2];
    if (base < NB && A < rem && A + s >= rem) {
        uint32_t acc = 0, bsel = (uint32_t)base, r = 1;
#pragma unroll
        for (int u = G - 1; u >= 0; --u) {
            if (A + acc + h[u] >= rem) { bsel = (uint32_t)(base + u); r = rem - A - acc; break; }
            acc += h[u];
        }
        misc[0] = bsel;
        misc[1] = r;
    }
    __syncthreads();
    *bucket_out = misc[0];
    *rem_out    = misc[1];
}

__global__ void __launch_bounds__(NT, 6)   // 3 blocks/CU (LDS 48.3KB); no spill (R8-proven)
rtdetr_post_kernel(const float* __restrict__ logits, const float* __restrict__ pboxes,
                   const float* __restrict__ sizes, float* __restrict__ out) {
    __shared__ float4   stage[NWAVE][DEPTH][64];     // 24 KB per-wave DMA rings
    __shared__ uint64_t cand[SELCAP];                // 8 KB
    __shared__ uint64_t srt[FINCAP];                 // 6 KB
    __shared__ uint32_t hist[NBH + 1];               // 8.2 KB (+sentinel, stays 0)
    __shared__ uint32_t part[NT];                    // 2 KB
    __shared__ uint32_t gsufx[65];
    __shared__ uint32_t misc[4];

    const int tid  = threadIdx.x;
    const int lane = tid & 63;
    const int wave = tid >> 6;
    const int b    = blockIdx.x;
    const float4* lg4 = reinterpret_cast<const float4*>(logits + (size_t)b * QC);

    for (int i = tid; i <= NBH; i += NT) hist[i] = 0;
    if (tid == 0) { misc[2] = 0; misc[3] = 0; }
    __syncthreads();   // init visible before stream pushes (drains nothing: no DMA yet)

    // ---- stream: per-wave 3-slot async ring, NO barriers in the loop ----
#pragma unroll
    for (int j = 0; j < DEPTH; ++j)        // rounds 0..2, max i4 = 511+1024 < 6000
        async_load16(lg4 + (tid + (j << 9)), &stage[wave][j][0]);

#pragma unroll
    for (int k = 0; k < 12; ++k) {
        float4 v = stage[wave][k % DEPTH][lane];   // compiler emits counted vmcnt
        if (k < 11 || tid < TAIL) {
            const int i4 = tid + (k << 9);
            float f[4] = { v.x, v.y, v.z, v.w };
#pragma unroll
            for (int c = 0; c < 4; ++c) {
                if (f[c] >= THRESH) {
                    uint32_t key = xform(__float_as_uint(f[c]));
                    uint32_t pos = atomicAdd(&misc[2], 1u);
                    uint32_t idx = 4u * (uint32_t)i4 + (uint32_t)c;
                    if (pos < SELCAP)
                        cand[pos] = ((uint64_t)key << 32) | (uint64_t)(0xFFFFFFFFu - idx);
                }
            }
        }
        if (k + DEPTH < 12) {
            int i4n = tid + ((k + DEPTH) << 9);
            if (i4n > NF4 - 1) i4n = NF4 - 1;      // round 11 tail: harmless dup load
            async_load16(lg4 + i4n, &stage[wave][k % DEPTH][0]);
        }
    }
    __syncthreads();

    const uint32_t cnt = misc[2];
    uint32_t n2;

    if (cnt >= RSEL && cnt <= FINCAP) {
        // ==== FAST PATH: all candidates are finalists; sigmoid in compact pass ====
        for (uint32_t i = tid; i < cnt; i += NT) {
            uint64_t e = cand[i];
            uint32_t k = (uint32_t)(e >> 32);
            uint32_t bits = (k & 0x80000000u) ? (k & 0x7FFFFFFFu) : ~k;
            float x  = __uint_as_float(bits);
            float sc = 1.0f / (1.0f + expf(-x));
            srt[i] = ((uint64_t)__float_as_uint(sc) << 32) | (uint64_t)(uint32_t)e;
        }
        n2 = cnt;
    } else {
        // ==== SLOW PATH (exactness fallback; ~never taken): re-read + radix ====
        if (tid == 0) misc[2] = 0;
        __syncthreads();
        for (int i4 = tid; i4 < NF4; i4 += NT) {
            float4 v = lg4[i4];
            atomicAdd(&hist[xform(__float_as_uint(v.x)) >> SH1], 1u);
            atomicAdd(&hist[xform(__float_as_uint(v.y)) >> SH1], 1u);
            atomicAdd(&hist[xform(__float_as_uint(v.z)) >> SH1], 1u);
            atomicAdd(&hist[xform(__float_as_uint(v.w)) >> SH1], 1u);
        }
        __syncthreads();
        uint32_t b1, r1;
        pick<NB1, true>(hist, part, gsufx, misc, tid, RSEL, &b1, &r1);  // re-zeroes hist
        for (int i4 = tid; i4 < NF4; i4 += NT) {
            float4 v = lg4[i4];
            uint32_t kk[4] = { xform(__float_as_uint(v.x)), xform(__float_as_uint(v.y)),
                               xform(__float_as_uint(v.z)), xform(__float_as_uint(v.w)) };
#pragma unroll
            for (int c = 0; c < 4; ++c) {
                uint32_t k = kk[c];
                uint32_t bk = k >> SH1;
                if (bk >= b1) {
                    uint32_t pos = atomicAdd(&misc[2], 1u);
                    uint32_t idx = 4u * (uint32_t)i4 + (uint32_t)c;
                    if (pos < SELCAP)
                        cand[pos] = ((uint64_t)k << 32) | (uint64_t)(0xFFFFFFFFu - idx);
                    if (bk == b1) atomicAdd(&hist[(k >> SH2) & 0xFFu], 1u);
                }
            }
        }
        __syncthreads();
        uint32_t t2, r2;
        pick<256, false>(hist, part, gsufx, misc, tid, r1, &t2, &r2);
        (void)r2;
        const uint32_t T2 = (b1 << SH1) | (t2 << SH2);
        uint32_t c2 = misc[2];
        uint32_t nn = c2 > SELCAP ? SELCAP : c2;
        for (uint32_t i = tid; i < nn; i += NT) {
            uint64_t e = cand[i];
            uint32_t k = (uint32_t)(e >> 32);
            if (k >= T2) {
                uint32_t bits = (k & 0x80000000u) ? (k & 0x7FFFFFFFu) : ~k;
                float x  = __uint_as_float(bits);
                float sc = 1.0f / (1.0f + expf(-x));
                uint32_t pos = atomicAdd(&misc[3], 1u);
                if (pos < FINCAP)
                    srt[pos] = ((uint64_t)__float_as_uint(sc) << 32) | (uint64_t)(uint32_t)e;
            }
        }
        __syncthreads();
        uint32_t m3 = misc[3];
        n2 = m3 > FINCAP ? FINCAP : m3;
        // re-zero refine-hist region dirtied by pick<256,false>
        for (int i = tid; i < 256; i += NT) hist[i] = 0;
    }
    __syncthreads();

    // ==== counting rank over srt[0..n2): O(n) ====
    // 1) histogram score buckets
    for (uint32_t i = tid; i < n2; i += NT)
        atomicAdd(&hist[sbucket((uint32_t)(srt[i] >> 32))], 1u);
    __syncthreads();

    // 2) suffix scan: hist[b] <- G[b] = #elements in buckets > b
    {
        const int base = tid * (NBH / NT);                // 4 buckets/thread
        uint32_t h0 = hist[base], h1 = hist[base + 1], h2 = hist[base + 2], h3 = hist[base + 3];
        part[tid] = h0 + h1 + h2 + h3;
        __syncthreads();
        if (tid < 64) {
            uint32_t gs = 0;
#pragma unroll
            for (int u = 0; u < 8; ++u) gs += part[(tid << 3) + u];
            uint32_t S = gs;
#pragma unroll
            for (int off = 1; off < 64; off <<= 1) {
                uint32_t v = __shfl_down(S, off, 64);
                if (tid + off < 64) S += v;
            }
            gsufx[tid] = S;
            if (tid == 0) gsufx[64] = 0;
        }
        __syncthreads();
        const int g8 = tid >> 3;
        uint32_t A = gsufx[g8 + 1];
        for (int t2 = tid + 1; t2 < ((g8 + 1) << 3); ++t2) A += part[t2];
        hist[base + 3] = A;
        hist[base + 2] = A + h3;
        hist[base + 1] = A + h3 + h2;
        hist[base + 0] = A + h3 + h2 + h1;
    }
    __syncthreads();

    // 3) scatter into bucket-sorted order; hist[b] -> S[b] (end offsets)
    for (uint32_t i = tid; i < n2; i += NT) {
        uint64_t k = srt[i];
        uint32_t slot = atomicAdd(&hist[sbucket((uint32_t)(k >> 32))], 1u);
        cand[slot] = k;
    }
    __syncthreads();

    // 4) exact rank = G[b] + same-bucket peers with greater (score,~idx) key
    for (uint32_t i = tid; i < n2; i += NT) {
        uint64_t my = srt[i];
        uint32_t bkt = sbucket((uint32_t)(my >> 32));
        uint32_t seg0 = hist[bkt + 1];      // = G[bkt]
        uint32_t seg1 = hist[bkt];          // = S[bkt]
        uint32_t rank = seg0;
        for (uint32_t j = seg0; j < seg1; ++j)
            rank += (cand[j] > my) ? 1u : 0u;
        if (rank < TOPK) {
            uint32_t idx = 0xFFFFFFFFu - (uint32_t)(my & 0xFFFFFFFFull);
            uint32_t lab = idx % NC;
            uint32_t q   = idx / NC;
            float4 bx = reinterpret_cast<const float4*>(pboxes)[(size_t)b * NQ + q];
            float sw = sizes[2 * b + 0];
            float sh = sizes[2 * b + 1];
            float hw = 0.5f * bx.z, hh = 0.5f * bx.w;
            float4 o;
            o.x = (bx.x - hw) * sw;
            o.y = (bx.y - hh) * sh;
            o.z = (bx.x + hw) * sw;
            o.w = (bx.y + hh) * sh;
            out[(size_t)b * TOPK + rank] = (float)lab;                                    // labels
            reinterpret_cast<float4*>(out + (size_t)NBATCH * TOPK)[(size_t)b * TOPK + rank] = o; // boxes
            out[(size_t)NBATCH * TOPK * 5 + (size_t)b * TOPK + rank] =
                __uint_as_float((uint32_t)(my >> 32));                                    // scores
        }
    }
}

extern "C" void kernel_launch(void* const* d_in, const int* in_sizes, int n_in,
                              void* d_out, int out_size, void* d_ws, size_t ws_size,
                              hipStream_t stream) {
    const float* logits = (const float*)d_in[0];   // [1024,300,80] f32
    const float* pboxes = (const float*)d_in[1];   // [1024,300,4]  f32
    const float* sizes  = (const float*)d_in[2];   // [1024,2]      f32
    float* out = (float*)d_out;                    // labels | boxes | scores (flat f32)

    hipLaunchKernelGGL(rtdetr_post_kernel, dim3(NBATCH), dim3(NT), 0, stream,
                       logits, pboxes, sizes, out);
}

// Round 15
// 28.590 us; speedup vs baseline: 1.1367x; 1.1367x over previous
//
#include <hip/hip_runtime.h>
#include <stdint.h>

// Problem constants
#define NBATCH 1024
#define NQ 300
#define NC 80
#define QC 24000       // NQ * NC floats per batch
#define NF4 6000       // QC / 4
#define TOPK 300
#define RSEL 384u      // fast-path lower guard / slow-path select rank
#define NT 512         // threads per block (8 waves)
#define NB1 2048       // slow-path coarse histogram buckets (key bits [31:21])
#define SH1 21
#define SH2 13         // slow-path refine bucket = (key >> 13) & 0xFF
#define SELCAP 2048    // candidate buffer
#define FINCAP 768     // finalist cap / fast-path upper guard
#define TAIL 368       // threads with a valid 12th round (6000 - 11*512)
#define THRESH 2.0f    // prefilter: candidate iff logit >= 2.0 (E[cnt]~546, sigma~23)
#define NBH 2048       // rank histogram buckets over score bits [20:10]
#define SBASE 0x3F600000u   // 0.875f; fast-path scores >= sigmoid(2.0)=0.8808

// order-preserving f32-bits -> u32 key (branchless)
__device__ __forceinline__ uint32_t xform(uint32_t u) {
    return u ^ (uint32_t)(((int32_t)u >> 31) | 0x80000000);
}

// monotone bucket map for score bits (exactness preserved via segment compare)
__device__ __forceinline__ uint32_t sbucket(uint32_t sbits) {
    int32_t d = (int32_t)(sbits - SBASE);
    d = d < 0 ? 0 : d;
    uint32_t bkt = ((uint32_t)d) >> 10;
    return bkt > (NBH - 1) ? (NBH - 1) : bkt;
}

// ---------------------------------------------------------------------------
// pick<NB,ZERO> (slow path only): hist[NB] finalized -> bucket from the top
// containing the rem-th largest + residual inside it. ZERO re-zeroes hist.
// NT=512 parameterization (wave0 lane sums 8 part entries).
// ---------------------------------------------------------------------------
template<int NB, bool ZERO>
__device__ __forceinline__ void pick(uint32_t* __restrict__ hist,
                                     uint32_t* __restrict__ part,
                                     uint32_t* __restrict__ gsufx,
                                     uint32_t* __restrict__ misc,
                                     int tid, uint32_t rem,
                                     uint32_t* bucket_out, uint32_t* rem_out) {
    constexpr int G = (NB >= NT) ? (NB / NT) : 1;
    const int base = tid * G;
    uint32_t h[G];
    uint32_t s = 0;
    if (base < NB) {
#pragma unroll
        for (int u = 0; u < G; ++u) { h[u] = hist[base + u]; s += h[u]; }
        if (ZERO) {
#pragma unroll
            for (int u = 0; u < G; ++u) hist[base + u] = 0;
        }
    } else {
#pragma unroll
        for (int u = 0; u < G; ++u) h[u] = 0;
    }
    part[tid] = s;
    __syncthreads();

    if (tid < 64) {
        uint32_t gs = 0;
#pragma unroll
        for (int u = 0; u < 8; ++u) gs += part[(tid << 3) + u];
        uint32_t S = gs;
#pragma unroll
        for (int off = 1; off < 64; off <<= 1) {
            uint32_t v = __shfl_down(S, off, 64);
            if (tid + off < 64) S += v;
        }
        gsufx[tid] = S;
        if (tid == 0) gsufx[64] = 0;
    }
    __syncthreads();

    const int g8 = tid >> 3;
    uint32_t A = gsufx[g8 + 1];
    for (int t2 = tid + 1; t2 < ((g8 + 1) << 3); ++t2) A += part[t2];
    if (base < NB && A < rem && A + s >= rem) {
        uint32_t acc = 0, bsel = (uint32_t)base, r = 1;
#pragma unroll
        for (int u = G - 1; u >= 0; --u) {
            if (A + acc + h[u] >= rem) { bsel = (uint32_t)(base + u); r = rem - A - acc; break; }
            acc += h[u];
        }
        misc[0] = bsel;
        misc[1] = r;
    }
    __syncthreads();
    *bucket_out = misc[0];
    *rem_out    = misc[1];
}

__global__ void __launch_bounds__(NT, 6)   // VGPR cap ~84: room for 12 live float4
rtdetr_post_kernel(const float* __restrict__ logits, const float* __restrict__ pboxes,
                   const float* __restrict__ sizes, float* __restrict__ out) {
    __shared__ __align__(16) uint32_t hist[NBH + 1];  // 8.2KB (+sentinel, stays 0)
    __shared__ uint64_t sel[SELCAP];                  // 16KB
    __shared__ uint64_t sel2[FINCAP];                 // 6KB finalist (score,~idx) keys
    __shared__ uint32_t part[NT];                     // 2KB
    __shared__ uint32_t gsufx[65];
    __shared__ uint32_t misc[4];

    const int tid = threadIdx.x;
    const int b   = blockIdx.x;
    const float4* lg4 = reinterpret_cast<const float4*>(logits + (size_t)b * QC);

    for (int i = tid; i <= NBH; i += NT) hist[i] = 0;
    if (tid == 0) { misc[2] = 0; misc[3] = 0; }
    __syncthreads();

    // ---- stream: all 12 loads issued up front, liveness FORCED via asm ----
    float4 va[12];
#pragma unroll
    for (int k = 0; k < 12; ++k) {
        int i4 = tid + (k << 9);
        if (i4 > NF4 - 1) i4 = NF4 - 1;        // clamp tail (processing stays guarded)
        va[k] = lg4[i4];
    }
#pragma unroll
    for (int k = 0; k < 12; ++k)               // forces 12 loads in flight, one waitcnt
        asm volatile("" :: "v"(va[k].x), "v"(va[k].y), "v"(va[k].z), "v"(va[k].w));

#pragma unroll
    for (int k = 0; k < 12; ++k) {
        if (k < 11 || tid < TAIL) {
            const int i4 = tid + (k << 9);
            float f[4] = { va[k].x, va[k].y, va[k].z, va[k].w };
#pragma unroll
            for (int c = 0; c < 4; ++c) {
                if (f[c] >= THRESH) {
                    uint32_t key = xform(__float_as_uint(f[c]));
                    uint32_t pos = atomicAdd(&misc[2], 1u);
                    uint32_t idx = 4u * (uint32_t)i4 + (uint32_t)c;
                    if (pos < SELCAP)
                        sel[pos] = ((uint64_t)key << 32) | (uint64_t)(0xFFFFFFFFu - idx);
                }
            }
        }
    }
    __syncthreads();

    const uint32_t cnt = misc[2];
    uint32_t n2;

    if (cnt >= RSEL && cnt <= FINCAP) {
        // ==== FAST PATH: all candidates are finalists; sigmoid in compact pass ====
        for (uint32_t i = tid; i < cnt; i += NT) {
            uint64_t e = sel[i];
            uint32_t k = (uint32_t)(e >> 32);
            uint32_t bits = (k & 0x80000000u) ? (k & 0x7FFFFFFFu) : ~k;
            float x  = __uint_as_float(bits);
            float sc = 1.0f / (1.0f + expf(-x));
            sel2[i] = ((uint64_t)__float_as_uint(sc) << 32) | (uint64_t)(uint32_t)e;
        }
        n2 = cnt;
    } else {
        // ==== SLOW PATH (exactness fallback; ~never taken): re-read + radix ====
        if (tid == 0) misc[2] = 0;
        __syncthreads();
        for (int i4 = tid; i4 < NF4; i4 += NT) {
            float4 v = lg4[i4];
            atomicAdd(&hist[xform(__float_as_uint(v.x)) >> SH1], 1u);
            atomicAdd(&hist[xform(__float_as_uint(v.y)) >> SH1], 1u);
            atomicAdd(&hist[xform(__float_as_uint(v.z)) >> SH1], 1u);
            atomicAdd(&hist[xform(__float_as_uint(v.w)) >> SH1], 1u);
        }
        __syncthreads();
        uint32_t b1, r1;
        pick<NB1, true>(hist, part, gsufx, misc, tid, RSEL, &b1, &r1);  // re-zeroes hist
        for (int i4 = tid; i4 < NF4; i4 += NT) {
            float4 v = lg4[i4];
            uint32_t kk[4] = { xform(__float_as_uint(v.x)), xform(__float_as_uint(v.y)),
                               xform(__float_as_uint(v.z)), xform(__float_as_uint(v.w)) };
#pragma unroll
            for (int c = 0; c < 4; ++c) {
                uint32_t k = kk[c];
                uint32_t bk = k >> SH1;
                if (bk >= b1) {
                    uint32_t pos = atomicAdd(&misc[2], 1u);
                    uint32_t idx = 4u * (uint32_t)i4 + (uint32_t)c;
                    if (pos < SELCAP)
                        sel[pos] = ((uint64_t)k << 32) | (uint64_t)(0xFFFFFFFFu - idx);
                    if (bk == b1) atomicAdd(&hist[(k >> SH2) & 0xFFu], 1u);
                }
            }
        }
        __syncthreads();
        uint32_t t2, r2;
        pick<256, false>(hist, part, gsufx, misc, tid, r1, &t2, &r2);
        (void)r2;
        const uint32_t T2 = (b1 << SH1) | (t2 << SH2);
        uint32_t c2 = misc[2];
        uint32_t nn = c2 > SELCAP ? SELCAP : c2;
        for (uint32_t i = tid; i < nn; i += NT) {
            uint64_t e = sel[i];
            uint32_t k = (uint32_t)(e >> 32);
            if (k >= T2) {
                uint32_t bits = (k & 0x80000000u) ? (k & 0x7FFFFFFFu) : ~k;
                float x  = __uint_as_float(bits);
                float sc = 1.0f / (1.0f + expf(-x));
                uint32_t pos = atomicAdd(&misc[3], 1u);
                if (pos < FINCAP)
                    sel2[pos] = ((uint64_t)__float_as_uint(sc) << 32) | (uint64_t)(uint32_t)e;
            }
        }
        __syncthreads();
        uint32_t m3 = misc[3];
        n2 = m3 > FINCAP ? FINCAP : m3;
        // re-zero refine-hist region dirtied by pick<256,false>
        for (int i = tid; i < 256; i += NT) hist[i] = 0;
    }
    __syncthreads();

    // ==== counting rank over sel2[0..n2): O(n) ====
    // 1) histogram score buckets
    for (uint32_t i = tid; i < n2; i += NT)
        atomicAdd(&hist[sbucket((uint32_t)(sel2[i] >> 32))], 1u);
    __syncthreads();

    // 2) suffix scan: hist[b] <- G[b] = #elements in buckets > b
    {
        const int base = tid * (NBH / NT);                // 4 buckets/thread
        uint32_t h0 = hist[base], h1 = hist[base + 1], h2 = hist[base + 2], h3 = hist[base + 3];
        part[tid] = h0 + h1 + h2 + h3;
        __syncthreads();
        if (tid < 64) {
            uint32_t gs = 0;
#pragma unroll
            for (int u = 0; u < 8; ++u) gs += part[(tid << 3) + u];
            uint32_t S = gs;
#pragma unroll
            for (int off = 1; off < 64; off <<= 1) {
                uint32_t v = __shfl_down(S, off, 64);
                if (tid + off < 64) S += v;
            }
            gsufx[tid] = S;
            if (tid == 0) gsufx[64] = 0;
        }
        __syncthreads();
        const int g8 = tid >> 3;
        uint32_t A = gsufx[g8 + 1];
        for (int t2 = tid + 1; t2 < ((g8 + 1) << 3); ++t2) A += part[t2];
        hist[base + 3] = A;
        hist[base + 2] = A + h3;
        hist[base + 1] = A + h3 + h2;
        hist[base + 0] = A + h3 + h2 + h1;
    }
    __syncthreads();

    // 3) scatter into bucket-sorted order; hist[b] -> S[b] (end offsets)
    for (uint32_t i = tid; i < n2; i += NT) {
        uint64_t k = sel2[i];
        uint32_t slot = atomicAdd(&hist[sbucket((uint32_t)(k >> 32))], 1u);
        sel[slot] = k;
    }
    __syncthreads();

    // 4) exact rank = G[b] + same-bucket peers with greater (score,~idx) key
    for (uint32_t i = tid; i < n2; i += NT) {
        uint64_t my = sel2[i];
        uint32_t bkt = sbucket((uint32_t)(my >> 32));
        uint32_t seg0 = hist[bkt + 1];      // = G[bkt]
        uint32_t seg1 = hist[bkt];          // = S[bkt]
        uint32_t rank = seg0;
        for (uint32_t j = seg0; j < seg1; ++j)
            rank += (sel[j] > my) ? 1u : 0u;
        if (rank < TOPK) {
            uint32_t idx = 0xFFFFFFFFu - (uint32_t)(my & 0xFFFFFFFFull);
            uint32_t lab = idx % NC;
            uint32_t q   = idx / NC;
            float4 bx = reinterpret_cast<const float4*>(pboxes)[(size_t)b * NQ + q];
            float sw = sizes[2 * b + 0];
            float sh = sizes[2 * b + 1];
            float hw = 0.5f * bx.z, hh = 0.5f * bx.w;
            float4 o;
            o.x = (bx.x - hw) * sw;
            o.y = (bx.y - hh) * sh;
            o.z = (bx.x + hw) * sw;
            o.w = (bx.y + hh) * sh;
            out[(size_t)b * TOPK + rank] = (float)lab;                                    // labels
            reinterpret_cast<float4*>(out + (size_t)NBATCH * TOPK)[(size_t)b * TOPK + rank] = o; // boxes
            out[(size_t)NBATCH * TOPK * 5 + (size_t)b * TOPK + rank] =
                __uint_as_float((uint32_t)(my >> 32));                                    // scores
        }
    }
}

extern "C" void kernel_launch(void* const* d_in, const int* in_sizes, int n_in,
                              void* d_out, int out_size, void* d_ws, size_t ws_size,
                              hipStream_t stream) {
    const float* logits = (const float*)d_in[0];   // [1024,300,80] f32
    const float* pboxes = (const float*)d_in[1];   // [1024,300,4]  f32
    const float* sizes  = (const float*)d_in[2];   // [1024,2]      f32
    float* out = (float*)d_out;                    // labels | boxes | scores (flat f32)

    hipLaunchKernelGGL(rtdetr_post_kernel, dim3(NBATCH), dim3(NT), 0, stream,
                       logits, pboxes, sizes, out);
}

// Round 16
// 24.901 us; speedup vs baseline: 1.3051x; 1.1481x over previous
//
#include <hip/hip_runtime.h>
#include <stdint.h>

// Problem constants
#define NBATCH 1024
#define NQ 300
#define NC 80
#define QC 24000       // NQ * NC floats per batch
#define NF4 6000       // QC / 4
#define TOPK 300
#define RSEL 384u      // fast-path lower guard / slow-path select rank
#define NT 512         // threads per block (8 waves)
#define NB1 2048       // slow-path coarse histogram buckets (key bits [31:21])
#define SH1 21
#define SH2 13         // slow-path refine bucket = (key >> 13) & 0xFF
#define SELCAP 2048    // candidate buffer
#define FINCAP 768     // finalist cap / fast-path upper guard
#define TAIL 368       // threads with a valid 12th float4 (6000 - 11*512)
#define THRESH 2.0f    // prefilter: candidate iff logit >= 2.0 (E[cnt]~546, sigma~23)
#define NBH 2048       // rank histogram buckets over score bits [20:10]
#define SBASE 0x3F600000u   // 0.875f; fast-path scores >= sigmoid(2.0)=0.8808

// order-preserving f32-bits -> u32 key (branchless)
__device__ __forceinline__ uint32_t xform(uint32_t u) {
    return u ^ (uint32_t)(((int32_t)u >> 31) | 0x80000000);
}

// monotone bucket map for score bits (exactness preserved via segment compare)
__device__ __forceinline__ uint32_t sbucket(uint32_t sbits) {
    int32_t d = (int32_t)(sbits - SBASE);
    d = d < 0 ? 0 : d;
    uint32_t bkt = ((uint32_t)d) >> 10;
    return bkt > (NBH - 1) ? (NBH - 1) : bkt;
}

// ---------------------------------------------------------------------------
// pick<NB,ZERO> (slow path only): hist[NB] finalized -> bucket from the top
// containing the rem-th largest + residual inside it. ZERO re-zeroes hist.
// NT=512 parameterization (wave0 lane sums 8 part entries).
// ---------------------------------------------------------------------------
template<int NB, bool ZERO>
__device__ __forceinline__ void pick(uint32_t* __restrict__ hist,
                                     uint32_t* __restrict__ part,
                                     uint32_t* __restrict__ gsufx,
                                     uint32_t* __restrict__ misc,
                                     int tid, uint32_t rem,
                                     uint32_t* bucket_out, uint32_t* rem_out) {
    constexpr int G = (NB >= NT) ? (NB / NT) : 1;
    const int base = tid * G;
    uint32_t h[G];
    uint32_t s = 0;
    if (base < NB) {
#pragma unroll
        for (int u = 0; u < G; ++u) { h[u] = hist[base + u]; s += h[u]; }
        if (ZERO) {
#pragma unroll
            for (int u = 0; u < G; ++u) hist[base + u] = 0;
        }
    } else {
#pragma unroll
        for (int u = 0; u < G; ++u) h[u] = 0;
    }
    part[tid] = s;
    __syncthreads();

    if (tid < 64) {
        uint32_t gs = 0;
#pragma unroll
        for (int u = 0; u < 8; ++u) gs += part[(tid << 3) + u];
        uint32_t S = gs;
#pragma unroll
        for (int off = 1; off < 64; off <<= 1) {
            uint32_t v = __shfl_down(S, off, 64);
            if (tid + off < 64) S += v;
        }
        gsufx[tid] = S;
        if (tid == 0) gsufx[64] = 0;
    }
    __syncthreads();

    const int g8 = tid >> 3;
    uint32_t A = gsufx[g8 + 1];
    for (int t2 = tid + 1; t2 < ((g8 + 1) << 3); ++t2) A += part[t2];
    if (base < NB && A < rem && A + s >= rem) {
        uint32_t acc = 0, bsel = (uint32_t)base, r = 1;
#pragma unroll
        for (int u = G - 1; u >= 0; --u) {
            if (A + acc + h[u] >= rem) { bsel = (uint32_t)(base + u); r = rem - A - acc; break; }
            acc += h[u];
        }
        misc[0] = bsel;
        misc[1] = r;
    }
    __syncthreads();
    *bucket_out = misc[0];
    *rem_out    = misc[1];
}

__global__ void __launch_bounds__(NT, 6)   // R8-proven occupancy point: no spill
rtdetr_post_kernel(const float* __restrict__ logits, const float* __restrict__ pboxes,
                   const float* __restrict__ sizes, float* __restrict__ out) {
    __shared__ __align__(16) uint32_t hist[NBH + 1];  // 8.2KB (+sentinel, stays 0)
    __shared__ uint64_t sel[SELCAP];                  // 16KB
    __shared__ uint64_t sel2[FINCAP];                 // 6KB finalist (score,~idx) keys
    __shared__ uint32_t part[NT];                     // 2KB
    __shared__ uint32_t gsufx[65];
    __shared__ uint32_t misc[4];

    const int tid = threadIdx.x;
    const int b   = blockIdx.x;
    const float4* lg4 = reinterpret_cast<const float4*>(logits + (size_t)b * QC);

    for (int i = tid; i <= NBH; i += NT) hist[i] = 0;
    if (tid == 0) { misc[2] = 0; misc[3] = 0; }
    __syncthreads();

    // ---- stream + prefilter: 1 v_cmp per element; xform+push only on hits ----
#pragma unroll
    for (int k = 0; k < 12; ++k) {
        if (k < 11 || tid < TAIL) {
            float4 v = lg4[tid + (k << 9)];
            const uint32_t i4 = (uint32_t)(tid + (k << 9));
            float f[4] = { v.x, v.y, v.z, v.w };
#pragma unroll
            for (int c = 0; c < 4; ++c) {
                if (f[c] >= THRESH) {
                    uint32_t key = xform(__float_as_uint(f[c]));
                    uint32_t pos = atomicAdd(&misc[2], 1u);
                    uint32_t idx = 4u * i4 + (uint32_t)c;
                    if (pos < SELCAP)
                        sel[pos] = ((uint64_t)key << 32) | (uint64_t)(0xFFFFFFFFu - idx);
                }
            }
        }
    }
    __syncthreads();

    const uint32_t cnt = misc[2];
    uint32_t n2;

    if (cnt >= RSEL && cnt <= FINCAP) {
        // ==== FAST PATH: all candidates finalists; sigmoid + rank-hist FUSED ====
        for (uint32_t i = tid; i < cnt; i += NT) {
            uint64_t e = sel[i];
            uint32_t k = (uint32_t)(e >> 32);
            uint32_t bits = (k & 0x80000000u) ? (k & 0x7FFFFFFFu) : ~k;
            float x  = __uint_as_float(bits);
            float sc = 1.0f / (1.0f + expf(-x));
            uint32_t sb = __float_as_uint(sc);
            sel2[i] = ((uint64_t)sb << 32) | (uint64_t)(uint32_t)e;
            atomicAdd(&hist[sbucket(sb)], 1u);     // fused rank histogram
        }
        n2 = cnt;
    } else {
        // ==== SLOW PATH (exactness fallback; ~never taken): re-read + radix ====
        if (tid == 0) misc[2] = 0;
        __syncthreads();
        for (int i4 = tid; i4 < NF4; i4 += NT) {
            float4 v = lg4[i4];
            atomicAdd(&hist[xform(__float_as_uint(v.x)) >> SH1], 1u);
            atomicAdd(&hist[xform(__float_as_uint(v.y)) >> SH1], 1u);
            atomicAdd(&hist[xform(__float_as_uint(v.z)) >> SH1], 1u);
            atomicAdd(&hist[xform(__float_as_uint(v.w)) >> SH1], 1u);
        }
        __syncthreads();
        uint32_t b1, r1;
        pick<NB1, true>(hist, part, gsufx, misc, tid, RSEL, &b1, &r1);  // re-zeroes hist
        for (int i4 = tid; i4 < NF4; i4 += NT) {
            float4 v = lg4[i4];
            uint32_t kk[4] = { xform(__float_as_uint(v.x)), xform(__float_as_uint(v.y)),
                               xform(__float_as_uint(v.z)), xform(__float_as_uint(v.w)) };
#pragma unroll
            for (int c = 0; c < 4; ++c) {
                uint32_t k = kk[c];
                uint32_t bk = k >> SH1;
                if (bk >= b1) {
                    uint32_t pos = atomicAdd(&misc[2], 1u);
                    uint32_t idx = 4u * (uint32_t)i4 + (uint32_t)c;
                    if (pos < SELCAP)
                        sel[pos] = ((uint64_t)k << 32) | (uint64_t)(0xFFFFFFFFu - idx);
                    if (bk == b1) atomicAdd(&hist[(k >> SH2) & 0xFFu], 1u);
                }
            }
        }
        __syncthreads();
        uint32_t t2, r2;
        pick<256, false>(hist, part, gsufx, misc, tid, r1, &t2, &r2);
        (void)r2;
        const uint32_t T2 = (b1 << SH1) | (t2 << SH2);
        uint32_t c2 = misc[2];
        uint32_t nn = c2 > SELCAP ? SELCAP : c2;
        for (uint32_t i = tid; i < nn; i += NT) {
            uint64_t e = sel[i];
            uint32_t k = (uint32_t)(e >> 32);
            if (k >= T2) {
                uint32_t bits = (k & 0x80000000u) ? (k & 0x7FFFFFFFu) : ~k;
                float x  = __uint_as_float(bits);
                float sc = 1.0f / (1.0f + expf(-x));
                uint32_t pos = atomicAdd(&misc[3], 1u);
                if (pos < FINCAP)
                    sel2[pos] = ((uint64_t)__float_as_uint(sc) << 32) | (uint64_t)(uint32_t)e;
            }
        }
        __syncthreads();
        uint32_t m3 = misc[3];
        n2 = m3 > FINCAP ? FINCAP : m3;
        // re-zero refine-hist region dirtied by pick<256,false>, then rank-hist
        for (int i = tid; i < 256; i += NT) hist[i] = 0;
        __syncthreads();
        for (uint32_t i = tid; i < n2; i += NT)
            atomicAdd(&hist[sbucket((uint32_t)(sel2[i] >> 32))], 1u);
    }
    __syncthreads();

    // ==== counting rank over sel2[0..n2): hist already holds bucket counts ====
    // suffix scan: hist[b] <- G[b] = #elements in buckets > b
    {
        const int base = tid * (NBH / NT);                // 4 buckets/thread
        uint32_t h0 = hist[base], h1 = hist[base + 1], h2 = hist[base + 2], h3 = hist[base + 3];
        part[tid] = h0 + h1 + h2 + h3;
        __syncthreads();
        if (tid < 64) {
            uint32_t gs = 0;
#pragma unroll
            for (int u = 0; u < 8; ++u) gs += part[(tid << 3) + u];
            uint32_t S = gs;
#pragma unroll
            for (int off = 1; off < 64; off <<= 1) {
                uint32_t v = __shfl_down(S, off, 64);
                if (tid + off < 64) S += v;
            }
            gsufx[tid] = S;
            if (tid == 0) gsufx[64] = 0;
        }
        __syncthreads();
        const int g8 = tid >> 3;
        uint32_t A = gsufx[g8 + 1];
        for (int t2 = tid + 1; t2 < ((g8 + 1) << 3); ++t2) A += part[t2];
        hist[base + 3] = A;
        hist[base + 2] = A + h3;
        hist[base + 1] = A + h3 + h2;
        hist[base + 0] = A + h3 + h2 + h1;
    }
    __syncthreads();

    // scatter into bucket-sorted order; hist[b] -> S[b] (end offsets)
    for (uint32_t i = tid; i < n2; i += NT) {
        uint64_t k = sel2[i];
        uint32_t slot = atomicAdd(&hist[sbucket((uint32_t)(k >> 32))], 1u);
        sel[slot] = k;
    }
    __syncthreads();

    // exact rank = G[b] + same-bucket peers with greater (score,~idx) key
    for (uint32_t i = tid; i < n2; i += NT) {
        uint64_t my = sel2[i];
        uint32_t bkt = sbucket((uint32_t)(my >> 32));
        uint32_t seg0 = hist[bkt + 1];      // = G[bkt]
        uint32_t seg1 = hist[bkt];          // = S[bkt]
        uint32_t rank = seg0;
        for (uint32_t j = seg0; j < seg1; ++j)
            rank += (sel[j] > my) ? 1u : 0u;
        if (rank < TOPK) {
            uint32_t idx = 0xFFFFFFFFu - (uint32_t)(my & 0xFFFFFFFFull);
            uint32_t lab = idx % NC;
            uint32_t q   = idx / NC;
            float4 bx = reinterpret_cast<const float4*>(pboxes)[(size_t)b * NQ + q];
            float sw = sizes[2 * b + 0];
            float sh = sizes[2 * b + 1];
            float hw = 0.5f * bx.z, hh = 0.5f * bx.w;
            float4 o;
            o.x = (bx.x - hw) * sw;
            o.y = (bx.y - hh) * sh;
            o.z = (bx.x + hw) * sw;
            o.w = (bx.y + hh) * sh;
            out[(size_t)b * TOPK + rank] = (float)lab;                                    // labels
            reinterpret_cast<float4*>(out + (size_t)NBATCH * TOPK)[(size_t)b * TOPK + rank] = o; // boxes
            out[(size_t)NBATCH * TOPK * 5 + (size_t)b * TOPK + rank] =
                __uint_as_float((uint32_t)(my >> 32));                                    // scores
        }
    }
}

extern "C" void kernel_launch(void* const* d_in, const int* in_sizes, int n_in,
                              void* d_out, int out_size, void* d_ws, size_t ws_size,
                              hipStream_t stream) {
    const float* logits = (const float*)d_in[0];   // [1024,300,80] f32
    const float* pboxes = (const float*)d_in[1];   // [1024,300,4]  f32
    const float* sizes  = (const float*)d_in[2];   // [1024,2]      f32
    float* out = (float*)d_out;                    // labels | boxes | scores (flat f32)

    hipLaunchKernelGGL(rtdetr_post_kernel, dim3(NBATCH), dim3(NT), 0, stream,
                       logits, pboxes, sizes, out);
}